// Round 1
// baseline (857.068 us; speedup 1.0000x reference)
//
#include <hip/hip_runtime.h>

typedef __attribute__((ext_vector_type(8))) short short8;    // 8 bf16 = 4 VGPRs
typedef __attribute__((ext_vector_type(4))) float float4v;   // MFMA acc

static __device__ __forceinline__ unsigned short f2bf(float x) {
    unsigned u = __float_as_uint(x);
    return (unsigned short)((u + 0x7fffu + ((u >> 16) & 1u)) >> 16);  // RNE
}
static __device__ __forceinline__ int imin(int a, int b) { return a < b ? a : b; }
static __device__ __forceinline__ int imax(int a, int b) { return a > b ? a : b; }

// ---------------------------------------------------------------------------
// Kernel 0: repack conv weights fp32 -> bf16, layout [cin_chunk8][tap9][cout128][cin32]
// ---------------------------------------------------------------------------
__global__ void wprep_kernel(const float* __restrict__ conv_w,
                             unsigned short* __restrict__ wprep) {
    int e = blockIdx.x * 256 + threadIdx.x;           // 294912 total
    if (e >= 294912) return;
    int ci = e & 31;
    int t2 = e >> 5;
    int co = t2 & 127;
    int t3 = t2 >> 7;        // chunk*9 + tap, 0..71
    int tap = t3 % 9;
    int chunk = t3 / 9;
    int cin = chunk * 32 + ci;
    int ty = tap / 3, tx = tap - ty * 3;
    wprep[e] = f2bf(conv_w[((co * 256 + cin) * 3 + ty) * 3 + tx]);
}

// ---------------------------------------------------------------------------
// Kernel 1: conv3x3 + bias + BN + ReLU, implicit GEMM via MFMA 16x16x32 bf16.
// Block: 256 thr (4 waves). Tile: 128 couts x (4 rows x 32 cols) pixels.
// Output: channels-last bf16 feat_cl[b][h][w][cout].
// ---------------------------------------------------------------------------
__global__ __launch_bounds__(256, 2) void conv_bn_relu_kernel(
    const float* __restrict__ feats,
    const float* __restrict__ conv_b,
    const float* __restrict__ bn_gamma,
    const float* __restrict__ bn_beta,
    const float* __restrict__ bn_mean,
    const float* __restrict__ bn_var,
    const unsigned short* __restrict__ wprep,
    unsigned short* __restrict__ feat_cl) {

    // input tile: 6 rows x 34 cols x 32 cin, cin contiguous, col stride padded
    // to 40 elems (80 B -> bank stride 20 -> ~2-way conflicts on frag reads).
    __shared__ __align__(16) unsigned short in_lds[6 * 34 * 40];
    __shared__ float aL[128], bL[128];

    const int tid = threadIdx.x;
    const int bx  = blockIdx.x;            // 2048 blocks: b(4) x ht(64) x wt(8)
    const int b   = bx >> 9;
    const int rem = bx & 511;
    const int h0  = (rem >> 3) * 4;
    const int w0  = (rem & 7) * 32;

    if (tid < 128) {
        float s = bn_gamma[tid] * rsqrtf(bn_var[tid] + 1e-5f);
        aL[tid] = s;
        bL[tid] = (conv_b[tid] - bn_mean[tid]) * s + bn_beta[tid];
    }

    const int wave = tid >> 6;
    const int lane = tid & 63;
    const int q    = lane >> 4;
    const int l15  = lane & 15;

    float4v acc[2][8];
#pragma unroll
    for (int a = 0; a < 2; ++a)
#pragma unroll
        for (int p = 0; p < 8; ++p)
            acc[a][p] = (float4v){0.f, 0.f, 0.f, 0.f};

    for (int chunk = 0; chunk < 8; ++chunk) {
        // ---- stage 32 cin x 6 rows x 34 cols fp32 -> bf16 LDS -------------
        const float* fb = feats + (size_t)(b * 256 + chunk * 32) * 65536;
#pragma unroll
        for (int it = 0; it < 26; ++it) {
            int e = tid + it * 256;                     // 6528 elements
            if (e < 6528) {
                int ci  = e / 204;                      // 6*34 = 204
                int rm  = e - ci * 204;
                int row = rm / 34;
                int col = rm - row * 34;
                int h = h0 - 1 + row;
                int w = w0 - 1 + col;
                float v = 0.f;                          // SAME zero padding
                if ((unsigned)h < 256u && (unsigned)w < 256u)
                    v = fb[ci * 65536 + h * 256 + w];
                in_lds[(row * 34 + col) * 40 + ci] = f2bf(v);
            }
        }
        __syncthreads();

        // ---- 9 taps x K=32 MFMA sweep ------------------------------------
#pragma unroll
        for (int tap = 0; tap < 9; ++tap) {
            const int dy = tap / 3, dx = tap - dy * 3;
            const short8* wpt = (const short8*)wprep + (chunk * 9 + tap) * 512;
            short8 a0 = wpt[(wave * 32 + l15) * 4 + q];          // couts m..m+15
            short8 a1 = wpt[(wave * 32 + 16 + l15) * 4 + q];     // couts m+16..m+31
#pragma unroll
            for (int pt = 0; pt < 8; ++pt) {
                const int r  = pt >> 1;
                const int c0 = (pt & 1) * 16;
                short8 bf = *(const short8*)&in_lds[((r + dy) * 34 + (c0 + l15 + dx)) * 40 + q * 8];
                acc[0][pt] = __builtin_amdgcn_mfma_f32_16x16x32_bf16(a0, bf, acc[0][pt], 0, 0, 0);
                acc[1][pt] = __builtin_amdgcn_mfma_f32_16x16x32_bf16(a1, bf, acc[1][pt], 0, 0, 0);
            }
        }
        __syncthreads();
    }

    // ---- epilogue: bias+BN+ReLU, channels-last bf16 store -----------------
#pragma unroll
    for (int ct = 0; ct < 2; ++ct) {
        const int coutb = wave * 32 + ct * 16 + q * 4;
        const float s0 = aL[coutb + 0], s1 = aL[coutb + 1];
        const float s2 = aL[coutb + 2], s3 = aL[coutb + 3];
        const float o0 = bL[coutb + 0], o1 = bL[coutb + 1];
        const float o2 = bL[coutb + 2], o3 = bL[coutb + 3];
#pragma unroll
        for (int pt = 0; pt < 8; ++pt) {
            const int r  = pt >> 1;
            const int cl = (pt & 1) * 16 + l15;
            float4v v = acc[ct][pt];
            unsigned short p0 = f2bf(fmaxf(v[0] * s0 + o0, 0.f));
            unsigned short p1 = f2bf(fmaxf(v[1] * s1 + o1, 0.f));
            unsigned short p2 = f2bf(fmaxf(v[2] * s2 + o2, 0.f));
            unsigned short p3 = f2bf(fmaxf(v[3] * s3 + o3, 0.f));
            unsigned long long pk = (unsigned long long)p0
                                  | ((unsigned long long)p1 << 16)
                                  | ((unsigned long long)p2 << 32)
                                  | ((unsigned long long)p3 << 48);
            size_t off = ((size_t)((b * 256 + h0 + r) * 256 + (w0 + cl))) * 128 + coutb;
            *(unsigned long long*)(feat_cl + off) = pk;
        }
    }
}

// ---------------------------------------------------------------------------
// Kernel 2: masked bilinear RoI gather. One block per roi (128 blocks).
// Phase 1: 256 threads compute per-position corner offsets + weights (LDS).
// Phase 2: threads = (64 channel-pairs x 4 positions), coalesced 4B loads.
// ---------------------------------------------------------------------------
__global__ __launch_bounds__(256) void roi_gather_kernel(
    const float* __restrict__ rois,
    const float* __restrict__ masks,
    const unsigned* __restrict__ feat_u32,    // feat_cl viewed as bf16x2
    float* __restrict__ out) {

    __shared__ int   offs[256][4];
    __shared__ float wts[256][4];

    const int roi = blockIdx.x;
    const int tid = threadIdx.x;
    const float* rp = rois + roi * 5;
    const int bi = (int)rp[0];
    int l_ = (int)(rp[1] * 0.25f - 1.0f);     // trunc toward 0 == astype(int32)
    int t_ = (int)(rp[2] * 0.25f - 1.0f);
    int r_ = (int)(rp[3] * 0.25f + 1.0f);
    int b_ = (int)(rp[4] * 0.25f + 1.0f);
    l_ = imin(imax(l_, 0), 256); t_ = imin(imax(t_, 0), 256);
    r_ = imin(imax(r_, 0), 256); b_ = imin(imax(b_, 0), 256);
    const float ch = (float)(b_ - t_);
    const float cw = (float)(r_ - l_);
    const bool transpose = ch > 1.5f * cw;
    const int chi = imax(b_ - t_, 1);
    const int cwi = imax(r_ - l_, 1);
    const float vscale = ((r_ > l_) && (b_ > t_)) ? 1.f : 0.f;

    {
        const int i = tid >> 5, j = tid & 31;      // pos = i*32 + j
        const float fi = (float)i + 0.5f, fj = (float)j + 0.5f;
        float V = transpose ? (fj * ch * (1.f / 32.f) - 0.5f)
                            : (fi * ch * (1.f / 8.f)  - 0.5f);
        float U = transpose ? (fi * cw * (1.f / 8.f)  - 0.5f)
                            : (fj * cw * (1.f / 32.f) - 0.5f);
        V = fmaxf(V, 0.f); U = fmaxf(U, 0.f);
        float vf = floorf(V), uf = floorf(U);
        int y0 = imin((int)vf, chi - 1); int y1 = imin(y0 + 1, chi - 1);
        int x0 = imin((int)uf, cwi - 1); int x1 = imin(x0 + 1, cwi - 1);
        float wy = V - vf, wx = U - uf;
        int ay0 = imin(imax(t_ + y0, 0), 255), ay1 = imin(imax(t_ + y1, 0), 255);
        int ax0 = imin(imax(l_ + x0, 0), 255), ax1 = imin(imax(l_ + x1, 0), 255);
        const float* mp = masks + (size_t)roi * 65536;
        wts[tid][0] = (1.f - wy) * (1.f - wx) * mp[ay0 * 256 + ax0] * vscale;
        wts[tid][1] = (1.f - wy) * wx         * mp[ay0 * 256 + ax1] * vscale;
        wts[tid][2] = wy * (1.f - wx)         * mp[ay1 * 256 + ax0] * vscale;
        wts[tid][3] = wy * wx                 * mp[ay1 * 256 + ax1] * vscale;
        offs[tid][0] = (ay0 * 256 + ax0) * 64;    // uint index into 128ch row
        offs[tid][1] = (ay0 * 256 + ax1) * 64;
        offs[tid][2] = (ay1 * 256 + ax0) * 64;
        offs[tid][3] = (ay1 * 256 + ax1) * 64;
    }
    __syncthreads();

    const int c2 = tid & 63;                  // channel pair: c = 2*c2
    const int pq = tid >> 6;                  // position phase 0..3
    const unsigned* fb = feat_u32 + (size_t)bi * (65536u * 64u) + c2;
    float* op = out + (size_t)roi * 32768 + c2 * 512;

#pragma unroll 4
    for (int po = 0; po < 64; ++po) {
        const int pos = po * 4 + pq;
        int   o0 = offs[pos][0], o1 = offs[pos][1], o2 = offs[pos][2], o3 = offs[pos][3];
        float w0 = wts[pos][0],  w1 = wts[pos][1],  w2 = wts[pos][2],  w3 = wts[pos][3];
        unsigned u0 = fb[o0], u1 = fb[o1], u2 = fb[o2], u3 = fb[o3];
        float lo = w0 * __uint_as_float(u0 << 16) + w1 * __uint_as_float(u1 << 16)
                 + w2 * __uint_as_float(u2 << 16) + w3 * __uint_as_float(u3 << 16);
        float hi = w0 * __uint_as_float(u0 & 0xffff0000u) + w1 * __uint_as_float(u1 & 0xffff0000u)
                 + w2 * __uint_as_float(u2 & 0xffff0000u) + w3 * __uint_as_float(u3 & 0xffff0000u);
        op[pos]       = lo;                   // channel 2*c2
        op[256 + pos] = hi;                   // channel 2*c2 + 1
    }
}

// ---------------------------------------------------------------------------
extern "C" void kernel_launch(void* const* d_in, const int* in_sizes, int n_in,
                              void* d_out, int out_size, void* d_ws, size_t ws_size,
                              hipStream_t stream) {
    const float* feats    = (const float*)d_in[0];
    const float* rois     = (const float*)d_in[1];
    const float* masks    = (const float*)d_in[2];
    const float* conv_w   = (const float*)d_in[3];
    const float* conv_b   = (const float*)d_in[4];
    const float* bn_gamma = (const float*)d_in[5];
    const float* bn_beta  = (const float*)d_in[6];
    const float* bn_mean  = (const float*)d_in[7];
    const float* bn_var   = (const float*)d_in[8];
    float* out = (float*)d_out;

    unsigned short* wprep   = (unsigned short*)d_ws;                      // 0.59 MB
    unsigned short* feat_cl = (unsigned short*)((char*)d_ws + (1 << 20)); // 64 MB

    hipLaunchKernelGGL(wprep_kernel, dim3(1152), dim3(256), 0, stream, conv_w, wprep);
    hipLaunchKernelGGL(conv_bn_relu_kernel, dim3(2048), dim3(256), 0, stream,
                       feats, conv_b, bn_gamma, bn_beta, bn_mean, bn_var,
                       wprep, feat_cl);
    hipLaunchKernelGGL(roi_gather_kernel, dim3(128), dim3(256), 0, stream,
                       rois, masks, (const unsigned*)feat_cl, out);
}

// Round 2
// 582.732 us; speedup vs baseline: 1.4708x; 1.4708x over previous
//
#include <hip/hip_runtime.h>

typedef __attribute__((ext_vector_type(8))) short short8;    // 8 bf16 = 4 VGPRs
typedef __attribute__((ext_vector_type(4))) float float4v;   // MFMA acc

static __device__ __forceinline__ unsigned short f2bf(float x) {
    unsigned u = __float_as_uint(x);
    return (unsigned short)((u + 0x7fffu + ((u >> 16) & 1u)) >> 16);  // RNE
}
static __device__ __forceinline__ int imin(int a, int b) { return a < b ? a : b; }
static __device__ __forceinline__ int imax(int a, int b) { return a > b ? a : b; }

// async global->LDS, 16B per lane; LDS side is wave-base + lane*16 (contiguous)
static __device__ __forceinline__ void gload_lds16(const void* g, void* l) {
    __builtin_amdgcn_global_load_lds(
        (const __attribute__((address_space(1))) void*)g,
        (__attribute__((address_space(3))) void*)l, 16, 0, 0);
}

// ---------------------------------------------------------------------------
// Kernel 0: repack conv weights fp32 -> bf16, [cin_chunk8][tap9][cout128][cin32]
//           + zero the 64B OOB guard block.
// ---------------------------------------------------------------------------
__global__ void wprep_kernel(const float* __restrict__ conv_w,
                             unsigned short* __restrict__ wprep,
                             unsigned short* __restrict__ zguard) {
    if (blockIdx.x == 0 && threadIdx.x < 32) zguard[threadIdx.x] = 0;
    int e = blockIdx.x * 256 + threadIdx.x;           // 294912 total
    if (e >= 294912) return;
    int ci = e & 31;
    int t2 = e >> 5;
    int co = t2 & 127;
    int t3 = t2 >> 7;        // chunk*9 + tap
    int tap = t3 % 9;
    int chunk = t3 / 9;
    int cin = chunk * 32 + ci;
    int ty = tap / 3, tx = tap - ty * 3;
    wprep[e] = f2bf(conv_w[((co * 256 + cin) * 3 + ty) * 3 + tx]);
}

// ---------------------------------------------------------------------------
// Kernel 1: per-batch input repack fp32 NCHW -> bf16 [chunk8][h][w][cin32].
// Block = one (chunk,h) row; thread = w. Coalesced 1KB reads per cin plane.
// ---------------------------------------------------------------------------
__global__ __launch_bounds__(256) void prep_kernel(const float* __restrict__ feats_b,
                                                   unsigned short* __restrict__ fb16) {
    const int bx = blockIdx.x;            // 2048: chunk(8) x h(256)
    const int chunk = bx >> 8;
    const int h = bx & 255;
    const int w = threadIdx.x;
    const float* src = feats_b + ((size_t)(chunk * 32) * 256 + h) * 256 + w;
    union { unsigned short u16[32]; short8 v8[4]; } p;
#pragma unroll
    for (int ci = 0; ci < 32; ++ci)
        p.u16[ci] = f2bf(src[(size_t)ci * 65536]);
    unsigned short* dst = fb16 + ((size_t)(chunk * 256 + h) * 256 + w) * 32;
#pragma unroll
    for (int k = 0; k < 4; ++k)
        *(short8*)(dst + k * 8) = p.v8[k];
}

// ---------------------------------------------------------------------------
// Kernel 2: conv3x3 + bias + BN + ReLU for one batch image, implicit GEMM.
// Block: 256 thr (4 waves), tile 128 couts x (4 rows x 32 cols). Staging via
// global_load_lds dwordx4 (13 wave-DMAs per chunk). Grid 512 = 2 blocks/CU.
// ---------------------------------------------------------------------------
__global__ __launch_bounds__(256, 2) void conv_bn_relu_kernel(
    const unsigned short* __restrict__ fb16,      // [chunk][h][w][cin32]
    const float* __restrict__ conv_b,
    const float* __restrict__ bn_gamma,
    const float* __restrict__ bn_beta,
    const float* __restrict__ bn_mean,
    const float* __restrict__ bn_var,
    const unsigned short* __restrict__ wprep,
    const unsigned short* __restrict__ zguard,
    unsigned short* __restrict__ feat_cl_b) {     // [h][w][128]

    __shared__ __align__(16) unsigned short in_lds[6 * 34 * 32];  // 13056 B
    __shared__ float aL[128], bL[128];

    const int tid = threadIdx.x;
    const int rem = blockIdx.x;            // 512: ht(64) x wt(8)
    const int h0  = (rem >> 3) * 4;
    const int w0  = (rem & 7) * 32;

    if (tid < 128) {
        float s = bn_gamma[tid] * rsqrtf(bn_var[tid] + 1e-5f);
        aL[tid] = s;
        bL[tid] = (conv_b[tid] - bn_mean[tid]) * s + bn_beta[tid];
    }

    const int wave = tid >> 6;
    const int lane = tid & 63;
    const int q    = lane >> 4;
    const int l15  = lane & 15;

    // ---- precompute per-lane staging descriptors (816 16B units total) ----
    // unit u: row=u/136, col=(u%136)>>2, part=(u%136)&3
    long off_s[4];          // element offset into fb16 chunk slice (shorts)
    int  lds_s[4];          // LDS short offset (= u*8, lane-contiguous)
    bool oob_s[4];
#pragma unroll
    for (int i = 0; i < 4; ++i) {
        int u = wave * 204 + i * 64 + lane;
        int row = u / 136;
        int r2  = u - row * 136;
        int col = r2 >> 2;
        int part = r2 & 3;
        int gh = h0 - 1 + row;
        int gw = w0 - 1 + col;
        oob_s[i] = ((unsigned)gh > 255u) || ((unsigned)gw > 255u);
        off_s[i] = (long)(gh * 256 + gw) * 32 + part * 8;
        lds_s[i] = u * 8;
    }

    float4v acc[2][8];
#pragma unroll
    for (int a = 0; a < 2; ++a)
#pragma unroll
        for (int p = 0; p < 8; ++p)
            acc[a][p] = (float4v){0.f, 0.f, 0.f, 0.f};

    for (int chunk = 0; chunk < 8; ++chunk) {
        const unsigned short* fb = fb16 + (size_t)chunk * (65536u * 32u);
#pragma unroll
        for (int i = 0; i < 3; ++i) {
            const unsigned short* gp = oob_s[i] ? zguard : (fb + off_s[i]);
            gload_lds16(gp, &in_lds[lds_s[i]]);
        }
        if (lane < 12) {
            const unsigned short* gp = oob_s[3] ? zguard : (fb + off_s[3]);
            gload_lds16(gp, &in_lds[lds_s[3]]);
        }
        __syncthreads();

#pragma unroll
        for (int tap = 0; tap < 9; ++tap) {
            const int dy = tap / 3, dx = tap - dy * 3;
            const short8* wpt = (const short8*)wprep + (chunk * 9 + tap) * 512;
            short8 a0 = wpt[(wave * 32 + l15) * 4 + q];          // couts m..m+15
            short8 a1 = wpt[(wave * 32 + 16 + l15) * 4 + q];     // couts m+16..m+31
#pragma unroll
            for (int pt = 0; pt < 8; ++pt) {
                const int r  = pt >> 1;
                const int c0 = (pt & 1) * 16;
                short8 bf = *(const short8*)&in_lds[((r + dy) * 34 + (c0 + l15 + dx)) * 32 + q * 8];
                acc[0][pt] = __builtin_amdgcn_mfma_f32_16x16x32_bf16(a0, bf, acc[0][pt], 0, 0, 0);
                acc[1][pt] = __builtin_amdgcn_mfma_f32_16x16x32_bf16(a1, bf, acc[1][pt], 0, 0, 0);
            }
        }
        __syncthreads();
    }

    // ---- epilogue: bias+BN+ReLU, channels-last bf16 store -----------------
#pragma unroll
    for (int ct = 0; ct < 2; ++ct) {
        const int coutb = wave * 32 + ct * 16 + q * 4;
        const float s0 = aL[coutb + 0], s1 = aL[coutb + 1];
        const float s2 = aL[coutb + 2], s3 = aL[coutb + 3];
        const float o0 = bL[coutb + 0], o1 = bL[coutb + 1];
        const float o2 = bL[coutb + 2], o3 = bL[coutb + 3];
#pragma unroll
        for (int pt = 0; pt < 8; ++pt) {
            const int r  = pt >> 1;
            const int cl = (pt & 1) * 16 + l15;
            float4v v = acc[ct][pt];
            unsigned short p0 = f2bf(fmaxf(v[0] * s0 + o0, 0.f));
            unsigned short p1 = f2bf(fmaxf(v[1] * s1 + o1, 0.f));
            unsigned short p2 = f2bf(fmaxf(v[2] * s2 + o2, 0.f));
            unsigned short p3 = f2bf(fmaxf(v[3] * s3 + o3, 0.f));
            unsigned long long pk = (unsigned long long)p0
                                  | ((unsigned long long)p1 << 16)
                                  | ((unsigned long long)p2 << 32)
                                  | ((unsigned long long)p3 << 48);
            size_t off = ((size_t)((h0 + r) * 256 + (w0 + cl))) * 128 + coutb;
            *(unsigned long long*)(feat_cl_b + off) = pk;
        }
    }
}

// ---------------------------------------------------------------------------
// Kernel 3: masked bilinear RoI gather. Block = (roi, quarter of positions).
// Phase 1: thread = (pos_local, corner) computes weight+offset into LDS.
// Phase 2: thread = (32 channel-quads x 8 pos-phases), 8B loads.
// ---------------------------------------------------------------------------
__global__ __launch_bounds__(256) void roi_gather_kernel(
    const float* __restrict__ rois,
    const float* __restrict__ masks,
    const unsigned long long* __restrict__ feat_u64,   // feat_cl as 4ch/8B
    float* __restrict__ out) {

    __shared__ int   offs[64][4];
    __shared__ float wts[64][4];

    const int blk = blockIdx.x;            // 512: roi(128) x q0(4)
    const int roi = blk >> 2;
    const int q0  = blk & 3;
    const int tid = threadIdx.x;

    const float* rp = rois + roi * 5;
    const int bi = (int)rp[0];
    int l_ = (int)(rp[1] * 0.25f - 1.0f);
    int t_ = (int)(rp[2] * 0.25f - 1.0f);
    int r_ = (int)(rp[3] * 0.25f + 1.0f);
    int b_ = (int)(rp[4] * 0.25f + 1.0f);
    l_ = imin(imax(l_, 0), 256); t_ = imin(imax(t_, 0), 256);
    r_ = imin(imax(r_, 0), 256); b_ = imin(imax(b_, 0), 256);
    const float ch = (float)(b_ - t_);
    const float cw = (float)(r_ - l_);
    const bool transpose = ch > 1.5f * cw;
    const int chi = imax(b_ - t_, 1);
    const int cwi = imax(r_ - l_, 1);
    const float vscale = ((r_ > l_) && (b_ > t_)) ? 1.f : 0.f;

    {
        const int pos_l  = tid >> 2;
        const int corner = tid & 3;
        const int pos = q0 * 64 + pos_l;
        const int i = pos >> 5, j = pos & 31;
        const float fi = (float)i + 0.5f, fj = (float)j + 0.5f;
        float V = transpose ? (fj * ch * (1.f / 32.f) - 0.5f)
                            : (fi * ch * (1.f / 8.f)  - 0.5f);
        float U = transpose ? (fi * cw * (1.f / 8.f)  - 0.5f)
                            : (fj * cw * (1.f / 32.f) - 0.5f);
        V = fmaxf(V, 0.f); U = fmaxf(U, 0.f);
        float vf = floorf(V), uf = floorf(U);
        int y0 = imin((int)vf, chi - 1); int y1 = imin(y0 + 1, chi - 1);
        int x0 = imin((int)uf, cwi - 1); int x1 = imin(x0 + 1, cwi - 1);
        float wy = V - vf, wx = U - uf;
        int ay = imin(imax(t_ + ((corner & 2) ? y1 : y0), 0), 255);
        int ax = imin(imax(l_ + ((corner & 1) ? x1 : x0), 0), 255);
        float wgt = ((corner & 2) ? wy : (1.f - wy)) * ((corner & 1) ? wx : (1.f - wx));
        wts[pos_l][corner]  = wgt * masks[(size_t)roi * 65536 + ay * 256 + ax] * vscale;
        offs[pos_l][corner] = (ay * 256 + ax) * 32;   // u64 units per pixel row
    }
    __syncthreads();

    const int cq = tid & 31;              // channel quad: ch = 4*cq..4*cq+3
    const int pq = tid >> 5;              // 0..7
    const unsigned long long* fb = feat_u64 + (size_t)bi * (65536ull * 32ull) + cq;
    float* op = out + (size_t)roi * 32768 + (size_t)cq * 4 * 256 + q0 * 64;

#pragma unroll 2
    for (int po = 0; po < 8; ++po) {
        const int pos_l = po * 8 + pq;
        float a0 = 0.f, a1 = 0.f, a2 = 0.f, a3 = 0.f;
#pragma unroll
        for (int k = 0; k < 4; ++k) {
            unsigned long long u = fb[offs[pos_l][k]];
            float w = wts[pos_l][k];
            a0 += w * __uint_as_float((unsigned)(u)       << 16);
            a1 += w * __uint_as_float((unsigned)(u >> 16) << 16);
            a2 += w * __uint_as_float((unsigned)(u >> 32) << 16);
            a3 += w * __uint_as_float((unsigned)(u >> 48) << 16);
        }
        op[pos_l]       = a0;
        op[pos_l + 256] = a1;
        op[pos_l + 512] = a2;
        op[pos_l + 768] = a3;
    }
}

// ---------------------------------------------------------------------------
extern "C" void kernel_launch(void* const* d_in, const int* in_sizes, int n_in,
                              void* d_out, int out_size, void* d_ws, size_t ws_size,
                              hipStream_t stream) {
    const float* feats    = (const float*)d_in[0];
    const float* rois     = (const float*)d_in[1];
    const float* masks    = (const float*)d_in[2];
    const float* conv_w   = (const float*)d_in[3];
    const float* conv_b   = (const float*)d_in[4];
    const float* bn_gamma = (const float*)d_in[5];
    const float* bn_beta  = (const float*)d_in[6];
    const float* bn_mean  = (const float*)d_in[7];
    const float* bn_var   = (const float*)d_in[8];
    float* out = (float*)d_out;

    // ws layout: [wprep 576KB][zguard 64B][... to 1MB][feat_cl 64MB][fb16 32MB]
    unsigned short* wprep   = (unsigned short*)d_ws;
    unsigned short* zguard  = (unsigned short*)((char*)d_ws + 0x90000);
    unsigned short* feat_cl = (unsigned short*)((char*)d_ws + (1ull << 20));
    unsigned short* fb16    = (unsigned short*)((char*)d_ws + (1ull << 20) + (64ull << 20));

    hipLaunchKernelGGL(wprep_kernel, dim3(1152), dim3(256), 0, stream,
                       conv_w, wprep, zguard);
    for (int b = 0; b < 4; ++b) {
        hipLaunchKernelGGL(prep_kernel, dim3(2048), dim3(256), 0, stream,
                           feats + (size_t)b * 256 * 65536, fb16);
        hipLaunchKernelGGL(conv_bn_relu_kernel, dim3(512), dim3(256), 0, stream,
                           fb16, conv_b, bn_gamma, bn_beta, bn_mean, bn_var,
                           wprep, zguard, feat_cl + (size_t)b * 65536 * 128);
    }
    hipLaunchKernelGGL(roi_gather_kernel, dim3(512), dim3(256), 0, stream,
                       rois, masks, (const unsigned long long*)feat_cl, out);
}